// Round 7
// baseline (370.977 us; speedup 1.0000x reference)
//
#include <hip/hip_runtime.h>
#include <hip/hip_bf16.h>
#include <stdint.h>

// Problem constants (from reference)
#define T_DIM   4
#define N_GRID  12288
#define C_DIM   16
#define NH      9
#define N_OUT   1024        // UP*E
#define K_DIM   144         // NH*C
#define M_TOTAL 196608      // B*V*T*N_GRID
#define MG_ELEMS (8 * T_DIM * N_GRID * C_DIM)   // 6291456

#define AS_STRIDE 146       // f16 elems/row (292B, odd-word stride -> conflict-free)
#define WROW      18        // W-slice LDS row stride (36B, odd-word -> conflict-free)
#define NITER     12        // 64-row tiles per persistent block

typedef __attribute__((ext_vector_type(4)))  float    f32x4;
typedef __attribute__((ext_vector_type(16))) float    f32x16;
typedef __attribute__((ext_vector_type(4)))  _Float16 f16x4;
typedef __attribute__((ext_vector_type(8)))  _Float16 f16x8;

// ---------------------------------------------------------------------------
// Pre-pass 1: W (144x1024 f32) -> f16 packed in MFMA B-fragment order for
// v_mfma_f32_32x32x16_f16 (layout verified by R1/R2 refcheck):
//   Wpk[((s*16+q)*64+lane)*16 + cg*8 + j] =
//     f16( W[(16*s + 8*(lane>>5) + j)*1024 + q*64 + cg*32 + (lane&31)] )
// ---------------------------------------------------------------------------
__global__ void pack_w_kernel(const float* __restrict__ W,
                              _Float16* __restrict__ Wpk) {
    const int gid  = blockIdx.x * blockDim.x + threadIdx.x;  // 0..18431
    const int cg   = gid & 1;
    const int lane = (gid >> 1) & 63;
    const int q    = (gid >> 7) & 15;
    const int s    = gid >> 11;          // 0..8
    const int l31  = lane & 31;
    const int lhi  = lane >> 5;

    _Float16 v[8];
#pragma unroll
    for (int j = 0; j < 8; ++j) {
        const int k   = 16 * s + 8 * lhi + j;             // 0..143
        const int col = q * 64 + cg * 32 + l31;           // 0..1023
        v[j] = (_Float16)W[k * N_OUT + col];
    }
    *(f16x8*)(Wpk + (size_t)gid * 8) = *(const f16x8*)v;
}

// ---------------------------------------------------------------------------
// Pre-pass 2: mg_emb f32 -> f16 (same layout). 25 MB -> 12.6 MB.
// ---------------------------------------------------------------------------
__global__ void conv_mg_kernel(const float* __restrict__ mg,
                               _Float16* __restrict__ mgh) {
    const size_t n4 = MG_ELEMS / 4;
    const size_t stride = (size_t)gridDim.x * blockDim.x;
    for (size_t i = (size_t)blockIdx.x * blockDim.x + threadIdx.x; i < n4; i += stride) {
        f32x4 f = *(const f32x4*)(mg + 4 * i);
        f16x4 h;
#pragma unroll
        for (int j = 0; j < 4; ++j) h[j] = (_Float16)f[j];
        *(f16x4*)(mgh + 4 * i) = h;
    }
}

// ---------------------------------------------------------------------------
// Main kernel: persistent blocks, W-slice resident in LDS, cached stores.
// Block = 256 threads (4 waves), tile 64 rows x 128 cols, NITER tiles/block.
// Wave w = (wr,wc): rows [wr*32,+32), cols [ntile*128 + wc*64, +64).
// LDS: W-slice 41.5 KB + A-tile 18.7 KB = 60.2 KB -> 2 blocks/CU resident.
// ---------------------------------------------------------------------------
__global__ __launch_bounds__(256) void mg_gemm_kernel(
    const _Float16* __restrict__ mgh,   // (8, 4, 12288, 16) f16
    const int*   __restrict__ vidx,     // (1, 4)
    const int*   __restrict__ adjc,     // (12288, 9)
    const _Float16* __restrict__ Wpk,   // packed B fragments
    const float* __restrict__ bias,     // (1024,)
    float* __restrict__ out)            // (196608, 1024) f32
{
    __shared__ _Float16 wlds[9 * 128 * WROW];   // 41472 B
    __shared__ _Float16 As[64 * AS_STRIDE];     // 18688 B

    const int b     = blockIdx.x;               // 0..2047
    const int ntile = b & 7;                    // col block 0..7 (128 cols each)
    const int mtb   = (b >> 3) * NITER;         // first 64-row tile
    const int tid   = threadIdx.x;
    const int lane  = tid & 63;
    const int w     = tid >> 6;                 // wave 0..3
    const int l31   = lane & 31;
    const int lhi   = lane >> 5;
    const int wr    = w >> 1;                   // row-half (32 rows)
    const int wc    = w & 1;                    // col-group (64 cols)

    // ---- load W slice (q = 2*ntile, 2*ntile+1) into LDS, once per block ----
    {
        const int half = tid & 1;
        const int r    = tid >> 1;              // 0..127
#pragma unroll
        for (int s = 0; s < 9; ++s) {
            const _Float16* sp = Wpk + (size_t)(s * 16 + ntile * 2) * 1024 + tid * 8;
            _Float16* dp = wlds + (s * 128 + r) * WROW + half * 8;
            *(f16x8*)dp = *(const f16x8*)sp;
        }
    }

    const int colbase = ntile * 128 + wc * 64 + l31;
    const float b0f = bias[colbase];
    const float b1f = bias[colbase + 32];

    // gather tasks: 576 per tile, 256 threads -> up to 3 tasks/thread
    const int task0 = tid;
    const int task1 = tid + 256;
    const int task2 = tid + 512;
    const bool has2 = (tid < 64);
    const int t0row = task0 / NH, t0nh = task0 - NH * t0row;
    const int t1row = task1 / NH, t1nh = task1 - NH * t1row;
    const int t2row = has2 ? (task2 / NH) : 0;
    const int t2nh  = has2 ? (task2 - NH * (task2 / NH)) : 0;

    f16x8 g0a, g0b, g1a, g1b, g2a, g2b;

    // ---- prologue: issue gather loads for tile 0 ----
    {
        const int r0m = mtb * 64;
        const int v   = r0m / (T_DIM * N_GRID);
        const int tt  = (r0m / N_GRID) & 3;
        const int p0  = r0m % N_GRID;
        const _Float16* src = mgh + (size_t)(vidx[v] * T_DIM + tt) * (N_GRID * C_DIM);
        const int ga = adjc[p0 * NH + task0];
        const int gb = adjc[p0 * NH + task1];
        g0a = *(const f16x8*)(src + (size_t)ga * C_DIM);
        g0b = *(const f16x8*)(src + (size_t)ga * C_DIM + 8);
        g1a = *(const f16x8*)(src + (size_t)gb * C_DIM);
        g1b = *(const f16x8*)(src + (size_t)gb * C_DIM + 8);
        if (has2) {
            const int gc = adjc[p0 * NH + task2];
            g2a = *(const f16x8*)(src + (size_t)gc * C_DIM);
            g2b = *(const f16x8*)(src + (size_t)gc * C_DIM + 8);
        }
    }

    for (int it = 0; it < NITER; ++it) {
        // ---- commit gathered regs into A-tile LDS ----
        {
            _Float16* d0 = As + t0row * AS_STRIDE + t0nh * C_DIM;
            *(f16x8*)d0 = g0a; *(f16x8*)(d0 + 8) = g0b;
            _Float16* d1 = As + t1row * AS_STRIDE + t1nh * C_DIM;
            *(f16x8*)d1 = g1a; *(f16x8*)(d1 + 8) = g1b;
            if (has2) {
                _Float16* d2 = As + t2row * AS_STRIDE + t2nh * C_DIM;
                *(f16x8*)d2 = g2a; *(f16x8*)(d2 + 8) = g2b;
            }
        }
        __syncthreads();   // A-tile (and on it=0, W-slice) visible to all waves

        const int r0m = (mtb + it) * 64;

        // ---- issue next tile's gather loads (fly under MFMA + stores) ----
        if (it + 1 < NITER) {
            const int r1m = r0m + 64;
            const int v   = r1m / (T_DIM * N_GRID);
            const int tt  = (r1m / N_GRID) & 3;
            const int p0  = r1m % N_GRID;
            const _Float16* src = mgh + (size_t)(vidx[v] * T_DIM + tt) * (N_GRID * C_DIM);
            const int ga = adjc[p0 * NH + task0];
            const int gb = adjc[p0 * NH + task1];
            g0a = *(const f16x8*)(src + (size_t)ga * C_DIM);
            g0b = *(const f16x8*)(src + (size_t)ga * C_DIM + 8);
            g1a = *(const f16x8*)(src + (size_t)gb * C_DIM);
            g1b = *(const f16x8*)(src + (size_t)gb * C_DIM + 8);
            if (has2) {
                const int gc = adjc[p0 * NH + task2];
                g2a = *(const f16x8*)(src + (size_t)gc * C_DIM);
                g2b = *(const f16x8*)(src + (size_t)gc * C_DIM + 8);
            }
        }

        // ---- MFMA: 32 rows x 64 cols per wave, B from LDS ----
        f32x16 acc0, acc1;
#pragma unroll
        for (int i = 0; i < 16; ++i) { acc0[i] = 0.f; acc1[i] = 0.f; }

        const _Float16* arow = As + (wr * 32 + l31) * AS_STRIDE + 8 * lhi;
        const _Float16* wp   = wlds + (wc * 64 + lane) * WROW;
#pragma unroll
        for (int s = 0; s < 9; ++s) {
            f16x8 a  = *(const f16x8*)(arow + s * C_DIM);
            const _Float16* bp = wp + s * (128 * WROW);
            f16x8 b0 = *(const f16x8*)(bp + 0);
            f16x8 b1 = *(const f16x8*)(bp + 8);
            acc0 = __builtin_amdgcn_mfma_f32_32x32x16_f16(a, b0, acc0, 0, 0, 0);
            acc1 = __builtin_amdgcn_mfma_f32_32x32x16_f16(a, b1, acc1, 0, 0, 0);
        }

        // ---- epilogue: add bias, plain cached stores ----
        float* outp = out + (size_t)(r0m + wr * 32) * N_OUT;
#pragma unroll
        for (int r = 0; r < 16; ++r) {
            const int rr = (r & 3) + 8 * (r >> 2) + 4 * lhi;   // 0..31
            outp[(size_t)rr * N_OUT + colbase]      = acc0[r] + b0f;
            outp[(size_t)rr * N_OUT + colbase + 32] = acc1[r] + b1f;
        }
        __syncthreads();   // protect As before next iteration's commit
    }
}

// ---------------------------------------------------------------------------
extern "C" void kernel_launch(void* const* d_in, const int* in_sizes, int n_in,
                              void* d_out, int out_size, void* d_ws, size_t ws_size,
                              hipStream_t stream) {
    const float* mg   = (const float*)d_in[0];   // mg_emb
    const int*   vidx = (const int*)  d_in[1];   // var_indices
    const int*   adjc = (const int*)  d_in[2];   // adjc
    const float* W    = (const float*)d_in[3];   // W
    const float* bias = (const float*)d_in[4];   // b
    float*       out  = (float*)d_out;

    _Float16* Wpk = (_Float16*)d_ws;                         // 294912 B
    _Float16* mgh = (_Float16*)((char*)d_ws + (1 << 20));    // 12.6 MB

    pack_w_kernel<<<dim3(72), dim3(256), 0, stream>>>(W, Wpk);
    conv_mg_kernel<<<dim3(1024), dim3(256), 0, stream>>>(mg, mgh);

    // persistent gather+GEMM: 2048 blocks x (12 tiles of 64 rows x 128 cols)
    mg_gemm_kernel<<<dim3(2048), dim3(256), 0, stream>>>(
        mgh, vidx, adjc, Wpk, bias, out);
}

// Round 8
// 151.796 us; speedup vs baseline: 2.4439x; 2.4439x over previous
//
#include <hip/hip_runtime.h>
#include <hip/hip_bf16.h>
#include <stdint.h>

// Problem constants (from reference)
#define T_DIM   4
#define N_GRID  12288
#define C_DIM   16
#define NH      9
#define N_OUT   1024        // UP*E
#define K_DIM   144         // NH*C
#define M_TOTAL 196608      // B*V*T*N_GRID  (16 slices of 12288 rows)
#define MG_ELEMS (8 * T_DIM * N_GRID * C_DIM)   // 6291456

#define AS_STRIDE 146       // f16 elems/row (292B, odd-word stride)
#define KSTEPS    9         // 144 / 16

typedef __attribute__((ext_vector_type(4)))  float    f32x4;
typedef __attribute__((ext_vector_type(16))) float    f32x16;
typedef __attribute__((ext_vector_type(4)))  _Float16 f16x4;
typedef __attribute__((ext_vector_type(8)))  _Float16 f16x8;

// ---------------------------------------------------------------------------
// Pre-pass 1: W (144x1024 f32) -> f16 packed in MFMA B-fragment order for
// v_mfma_f32_32x32x16_f16 (layout verified by R1/R2 refcheck):
//   Wpk[((s*16+q)*64+lane)*16 + cg*8 + j] =
//     f16( W[(16*s + 8*(lane>>5) + j)*1024 + q*64 + cg*32 + (lane&31)] )
// ---------------------------------------------------------------------------
__global__ void pack_w_kernel(const float* __restrict__ W,
                              _Float16* __restrict__ Wpk) {
    const int gid  = blockIdx.x * blockDim.x + threadIdx.x;  // 0..18431
    const int cg   = gid & 1;
    const int lane = (gid >> 1) & 63;
    const int q    = (gid >> 7) & 15;
    const int s    = gid >> 11;          // 0..8
    const int l31  = lane & 31;
    const int lhi  = lane >> 5;

    _Float16 v[8];
#pragma unroll
    for (int j = 0; j < 8; ++j) {
        const int k   = 16 * s + 8 * lhi + j;             // 0..143
        const int col = q * 64 + cg * 32 + l31;           // 0..1023
        v[j] = (_Float16)W[k * N_OUT + col];
    }
    *(f16x8*)(Wpk + (size_t)gid * 8) = *(const f16x8*)v;
}

// ---------------------------------------------------------------------------
// Pre-pass 2: mg_emb f32 -> f16 (same layout). 25 MB -> 12.6 MB; one (v,t)
// slice = 393 KB so two slices + Wpk stay L2-resident per XCD.
// ---------------------------------------------------------------------------
__global__ void conv_mg_kernel(const float* __restrict__ mg,
                               _Float16* __restrict__ mgh) {
    const size_t n4 = MG_ELEMS / 4;
    const size_t stride = (size_t)gridDim.x * blockDim.x;
    for (size_t i = (size_t)blockIdx.x * blockDim.x + threadIdx.x; i < n4; i += stride) {
        f32x4 f = *(const f32x4*)(mg + 4 * i);
        f16x4 h;
#pragma unroll
        for (int j = 0; j < 4; ++j) h[j] = (_Float16)f[j];
        *(f16x4*)(mgh + 4 * i) = h;
    }
}

// ---------------------------------------------------------------------------
// Main kernel (R2 structure + XCD slice pinning + f16 gather + NT stores).
// Block = 512 threads (8 waves), tile 64 rows x 512 cols.
// Swizzle: xcd = bid&7 owns slices {2*xcd, 2*xcd+1}; its 768 blocks iterate
// 192 row-tiles x 2 ytiles per slice -> per-XCD L2 read set ~1.1 MB resident.
// ---------------------------------------------------------------------------
__global__ __launch_bounds__(512, 4) void mg_gemm_kernel(
    const _Float16* __restrict__ mgh,   // (8, 4, 12288, 16) f16
    const int*   __restrict__ vidx,     // (1, 4)
    const int*   __restrict__ adjc,     // (12288, 9)
    const _Float16* __restrict__ Wpk,   // packed B fragments
    const float* __restrict__ bias,     // (1024,)
    float* __restrict__ out)            // (196608, 1024) f32
{
    __shared__ _Float16 As[64 * AS_STRIDE];   // 18.7 KB

    // ---- XCD-pinned decode of blockIdx.x (0..6143) ----
    const int b     = blockIdx.x;
    const int xcd   = b & 7;               // round-robin XCD heuristic
    const int j     = b >> 3;              // 0..767 within XCD
    const int sl    = j / 384;             // 0..1: which of this XCD's 2 slices
    const int jj    = j - sl * 384;        // 0..383
    const int slice = xcd * 2 + sl;        // 0..15 == v*4 + t
    const int mloc  = jj >> 1;             // 0..191 row-tile within slice
    const int ytile = jj & 1;              // 0..1 col half

    const int v     = slice >> 2;
    const int t     = slice & 3;
    const int p0    = mloc * 64;           // start grid point
    const int r0    = slice * N_GRID + p0; // global output row base
    const int vi    = vidx[v];
    const _Float16* src = mgh + (size_t)(vi * T_DIM + t) * N_GRID * C_DIM;

    const int tid = threadIdx.x;

    // ---- stage A tile: 64 rows x 9 neighbors x 16 ch (f16, no cvt) ----
    for (int task = tid; task < 64 * NH; task += 512) {
        const int row = task / NH;
        const int nh  = task - row * NH;
        const int g   = adjc[p0 * NH + task];        // == adjc[(p0+row)*9 + nh]
        const _Float16* sp = src + (size_t)g * C_DIM;
        _Float16* dst = As + row * AS_STRIDE + nh * C_DIM;
        *(f16x8*)dst       = *(const f16x8*)sp;
        *(f16x8*)(dst + 8) = *(const f16x8*)(sp + 8);
    }
    __syncthreads();

    const int lane = tid & 63;
    const int w    = tid >> 6;             // wave 0..7
    const int l31  = lane & 31;
    const int lhi  = lane >> 5;
    const int q    = ytile * 8 + w;        // col-group 0..15

    f32x16 acc00, acc01, acc10, acc11;     // [colhalf][rowhalf]
#pragma unroll
    for (int i = 0; i < 16; ++i) { acc00[i]=0.f; acc01[i]=0.f; acc10[i]=0.f; acc11[i]=0.f; }

    const _Float16* arow0 = As + l31 * AS_STRIDE + 8 * lhi;
    const _Float16* arow1 = arow0 + 32 * AS_STRIDE;
    const _Float16* wp    = Wpk + ((size_t)q * 64 + lane) * 16;

#pragma unroll
    for (int s = 0; s < KSTEPS; ++s) {
        f16x8 a0 = *(const f16x8*)(arow0 + s * C_DIM);
        f16x8 a1 = *(const f16x8*)(arow1 + s * C_DIM);
        const _Float16* bp = wp + (size_t)s * (16 * 64 * 16);
        f16x8 b0 = *(const f16x8*)(bp + 0);
        f16x8 b1 = *(const f16x8*)(bp + 8);
        acc00 = __builtin_amdgcn_mfma_f32_32x32x16_f16(a0, b0, acc00, 0, 0, 0);
        acc01 = __builtin_amdgcn_mfma_f32_32x32x16_f16(a1, b0, acc01, 0, 0, 0);
        acc10 = __builtin_amdgcn_mfma_f32_32x32x16_f16(a0, b1, acc10, 0, 0, 0);
        acc11 = __builtin_amdgcn_mfma_f32_32x32x16_f16(a1, b1, acc11, 0, 0, 0);
    }

    // ---- epilogue: add bias, NT scattered stores (writes bypass L2) ----
    const int colbase = q * 64 + l31;
    const float b0f = bias[colbase];
    const float b1f = bias[colbase + 32];
    float* outp = out + (size_t)r0 * N_OUT;

#pragma unroll
    for (int r = 0; r < 16; ++r) {
        const int rr = (r & 3) + 8 * (r >> 2) + 4 * lhi;   // 0..31
        __builtin_nontemporal_store(acc00[r] + b0f, &outp[(size_t)rr * N_OUT + colbase]);
        __builtin_nontemporal_store(acc10[r] + b1f, &outp[(size_t)rr * N_OUT + colbase + 32]);
        __builtin_nontemporal_store(acc01[r] + b0f, &outp[(size_t)(rr + 32) * N_OUT + colbase]);
        __builtin_nontemporal_store(acc11[r] + b1f, &outp[(size_t)(rr + 32) * N_OUT + colbase + 32]);
    }
}

// ---------------------------------------------------------------------------
extern "C" void kernel_launch(void* const* d_in, const int* in_sizes, int n_in,
                              void* d_out, int out_size, void* d_ws, size_t ws_size,
                              hipStream_t stream) {
    const float* mg   = (const float*)d_in[0];   // mg_emb
    const int*   vidx = (const int*)  d_in[1];   // var_indices
    const int*   adjc = (const int*)  d_in[2];   // adjc
    const float* W    = (const float*)d_in[3];   // W
    const float* bias = (const float*)d_in[4];   // b
    float*       out  = (float*)d_out;

    _Float16* Wpk = (_Float16*)d_ws;                         // 294912 B
    _Float16* mgh = (_Float16*)((char*)d_ws + (1 << 20));    // 12.6 MB

    pack_w_kernel<<<dim3(72), dim3(256), 0, stream>>>(W, Wpk);
    conv_mg_kernel<<<dim3(1024), dim3(256), 0, stream>>>(mg, mgh);

    // gather+GEMM: 64x512 tiles, XCD-pinned slices, NT stores
    mg_gemm_kernel<<<dim3(M_TOTAL / 64 * 2), dim3(512), 0, stream>>>(
        mgh, vidx, adjc, Wpk, bias, out);
}